// Round 11
// baseline (170.554 us; speedup 1.0000x reference)
//
#include <hip/hip_runtime.h>
#include <hip/hip_bf16.h>

typedef short short8 __attribute__((ext_vector_type(8)));
typedef float f32x4 __attribute__((ext_vector_type(4)));
typedef unsigned uint4v __attribute__((ext_vector_type(4)));

#define F 32
#define NB 4
#define BINSH 5          // 32 nodes per dst-bin
#define BINSZ 32
#define EPB 512          // edges per Phase-A block
#define CAPB 2048        // reduce: rows permuted per chunk
#define SCH2 8192        // edges per sort block (new path)
#define MAXBIN2 1600     // new path: nbin limit (LDS hist 9*1600*4B = 57.6 KB)
#define NKEYMAX (9 * MAXBIN2)
#define NBLK2MAX 128
// old path constants
#define OSCH 2048
#define OMAXNBLK 1024

__device__ __forceinline__ short f2bf(float f) {   // RNE f32->bf16
    unsigned u = __float_as_uint(f);
    unsigned r = (u + 0x7FFFu + ((u >> 16) & 1u)) >> 16;
    return (short)r;
}

__device__ __forceinline__ unsigned pk2(float a, float b) {  // packed bf16 pair
    __hip_bfloat162 h = __float22bfloat162_rn(make_float2(a, b));
    union { __hip_bfloat162 h; unsigned u; } cv; cv.h = h; return cv.u;
}

// -------- weight prep: bf16 B-fragment layout into ws (32 KB, L2-resident) --
__global__ __launch_bounds__(256) void w_prep(
    const float* __restrict__ w, short* __restrict__ wbf)
{
    int idx = blockIdx.x * 256 + threadIdx.x;   // 64 x 256 = 16384
    int k = idx >> 10, rem = idx & 1023, i = rem >> 5, o = rem & 31;
    int slot = (((k * 4 + (i >> 3)) * 2 + (o >> 4)) * 16 + (o & 15)) * 8 + (i & 7);
    wbf[slot] = f2bf(w[idx]);
}

// ================== NEW SORT: key = cell*nbin + bin, no atomics/memset ======

// K1: per-block joint histogram -> counts[b][k] (every slot written)
__global__ __launch_bounds__(256) void k1_hist(
    const int* __restrict__ ei, const float* __restrict__ attr, int E,
    int nbin, int nkey, int* __restrict__ counts)
{
    __shared__ int h[NKEYMAX];
    int t = threadIdx.x, b = blockIdx.x;
    for (int i = t; i < nkey; i += 256) h[i] = 0;
    __syncthreads();
    int start = b * SCH2, end = min(start + SCH2, E);
    for (int e = start + t; e < end; e += 256) {
        int dst = ei[e];
        float2 a = reinterpret_cast<const float2*>(attr)[e];
        float tx = fminf(fmaxf((a.x + 1.0f) * 1.5f, 0.f), 3.f);
        float ty = fminf(fmaxf((a.y + 1.0f) * 1.5f, 0.f), 3.f);
        int kx = min((int)tx, 2), ky = min((int)ty, 2);
        atomicAdd(&h[(kx * 3 + ky) * nbin + (dst >> BINSH)], 1);  // LDS only
    }
    __syncthreads();
    int* d = counts + (size_t)b * nkey;
    for (int i = t; i < nkey; i += 256) d[i] = h[i];
}

// K2a: keytot[k] = sum_b counts[b][k]
__global__ __launch_bounds__(256) void k2a_tot(
    const int* __restrict__ counts, int* __restrict__ keytot,
    int nkey, int nblk)
{
    int k = blockIdx.x * 256 + threadIdx.x;
    if (k >= nkey) return;
    int s = 0;
    for (int b = 0; b < nblk; ++b) s += counts[(size_t)b * nkey + k];
    keytot[k] = s;
}

// K2b: exclusive scan keytot -> keybase; derive blkoff (Phase-A block ranges)
__global__ __launch_bounds__(256) void k2b_scan(
    const int* __restrict__ keytot, int* __restrict__ keybase,
    int* __restrict__ blkoff, int nkey, int nbin, int Etot)
{
    __shared__ int part[256];
    int t = threadIdx.x;
    int chunk = (nkey + 255) / 256;
    int lo = t * chunk, hi = min(lo + chunk, nkey);
    int s = 0;
    for (int q = lo; q < hi; ++q) s += keytot[q];
    part[t] = s;
    __syncthreads();
    if (t == 0) {
        int run = 0;
        for (int j = 0; j < 256; ++j) { int v = part[j]; part[j] = run; run += v; }
        keybase[nkey] = Etot;
    }
    __syncthreads();
    int run = part[t];
    for (int q = lo; q < hi; ++q) { keybase[q] = run; run += keytot[q]; }
    __syncthreads();
    if (t == 0) {
        int boff = 0;
        for (int c = 0; c < 9; ++c) {
            blkoff[c] = boff;
            int cs = keybase[c * nbin];
            int ce = keybase[(c + 1) * nbin];   // c=8 -> keybase[nkey]=Etot
            boff += (ce - cs + EPB - 1) / EPB;
        }
        blkoff[9] = boff;
    }
}

// K2c: counts[b][k] <- global base for that (block,key)
__global__ __launch_bounds__(256) void k2c_base(
    int* __restrict__ counts, const int* __restrict__ keybase,
    int nkey, int nblk)
{
    int k = blockIdx.x * 256 + threadIdx.x;
    if (k >= nkey) return;
    int run = keybase[k];
    for (int b = 0; b < nblk; ++b) {
        size_t idx = (size_t)b * nkey + k;
        int v = counts[idx];
        counts[idx] = run;
        run += v;
    }
}

// K3: scatter. rec = {src u16 | txq u16, tyq u16 | dloc<<16}; dloc8[pos]
__global__ __launch_bounds__(256) void k3_scat(
    const int* __restrict__ ei, const float* __restrict__ attr, int E,
    int nbin, int nkey, const int* __restrict__ counts,
    uint2* __restrict__ rec, unsigned char* __restrict__ dloc8)
{
    __shared__ int cur[NKEYMAX];
    int t = threadIdx.x, b = blockIdx.x;
    const int* base = counts + (size_t)b * nkey;
    for (int i = t; i < nkey; i += 256) cur[i] = base[i];
    __syncthreads();
    int start = b * SCH2, end = min(start + SCH2, E);
    for (int e = start + t; e < end; e += 256) {
        int dst = ei[e];
        int sn  = ei[E + e];
        float2 a = reinterpret_cast<const float2*>(attr)[e];
        float tx = fminf(fmaxf((a.x + 1.0f) * 1.5f, 0.f), 3.f);
        float ty = fminf(fmaxf((a.y + 1.0f) * 1.5f, 0.f), 3.f);
        int kx = min((int)tx, 2), ky = min((int)ty, 2);
        int k = (kx * 3 + ky) * nbin + (dst >> BINSH);
        int pos = atomicAdd(&cur[k], 1);           // LDS rank
        unsigned txq = (unsigned)(tx * 21845.0f + 0.5f);
        unsigned tyq = (unsigned)(ty * 21845.0f + 0.5f);
        uint2 r;
        r.x = (unsigned)sn | (txq << 16);
        r.y = tyq | ((unsigned)(dst & (BINSZ - 1)) << 16);
        rec[pos] = r;
        dloc8[pos] = (unsigned char)(dst & (BINSZ - 1));
    }
}

// -------- Phase A: cell-sorted tiles -> bf16 msg rows, FULLY STREAMING ------
// msg row p (64 B) corresponds to record p; wave writes contiguous 1 KB tile.
__global__ __launch_bounds__(256, 4) void bconv_msgS(
    const float* __restrict__ x_j, const short* __restrict__ wbf,
    const int* __restrict__ keybase, const int* __restrict__ blkoff,
    const uint2* __restrict__ rec, unsigned* __restrict__ msg, int nbin)
{
    int b = blockIdx.x;
    if (b >= blkoff[9]) return;
    int c = 0;
    #pragma unroll
    for (int q = 1; q < 9; ++q) c += (b >= blkoff[q]) ? 1 : 0;
    int kx0 = c / 3, ky0 = c - 3 * (c / 3);
    int local  = b - blkoff[c];
    int cstart = keybase[c * nbin];
    int cend   = keybase[(c + 1) * nbin];
    int pstart = cstart + local * EPB;
    int pend   = min(pstart + EPB, cend);
    if (pstart >= pend) return;

    int t = threadIdx.x;
    int wid = t >> 6, lane = t & 63;
    int row16 = lane & 15, hi = lane >> 4;

    short8 w0[4], w1[4];
    #pragma unroll
    for (int kk = 0; kk < 4; ++kk) {
        int ks = (kx0 + (kk >> 1)) * NB + (ky0 + (kk & 1));
        w0[kk] = *reinterpret_cast<const short8*>(
            wbf + (((ks * 4 + hi) * 2 + 0) * 16 + row16) * 8);
        w1[kk] = *reinterpret_cast<const short8*>(
            wbf + (((ks * 4 + hi) * 2 + 1) * 16 + row16) * 8);
    }

    const float4* x4 = reinterpret_cast<const float4*>(x_j);
    int ntile = (pend - pstart + 15) >> 4;

    auto fetch = [&](int ti, uint2& r2, float4& fa, float4& fb) {
        int p = pstart + ti * 16 + row16;
        int pp = min(p, pend - 1);
        r2 = rec[pp];
        int sn = r2.x & 0xFFFF;
        fa = x4[sn * 8 + 2 * hi];
        fb = x4[sn * 8 + 2 * hi + 1];
    };

    int it = wid;
    uint2 r2; float4 fa, fb;
    if (it < ntile) fetch(it, r2, fa, fb);

    for (; it < ntile; it += 4) {
        uint2 r2N; float4 faN, fbN;
        bool hn = (it + 4) < ntile;
        if (hn) fetch(it + 4, r2N, faN, fbN);      // loads fly under compute

        float tx = (float)(r2.x >> 16)     * (1.f / 21845.f);
        float ty = (float)(r2.y & 0xFFFF)  * (1.f / 21845.f);
        float fx = tx - (float)kx0, fy = ty - (float)ky0;
        float bx0 = 1.f - fx, by0 = 1.f - fy;
        float bc[4] = { bx0 * by0, bx0 * fy, fx * by0, fx * fy };
        float fl[8] = { fa.x, fa.y, fa.z, fa.w, fb.x, fb.y, fb.z, fb.w };

        f32x4 a0 = {0,0,0,0}, a1 = {0,0,0,0};
        #pragma unroll
        for (int kk = 0; kk < 4; ++kk) {
            float s = bc[kk];
            uint4v u;
            u[0] = pk2(fl[0] * s, fl[1] * s);
            u[1] = pk2(fl[2] * s, fl[3] * s);
            u[2] = pk2(fl[4] * s, fl[5] * s);
            u[3] = pk2(fl[6] * s, fl[7] * s);
            short8 av = __builtin_bit_cast(short8, u);
            a0 = __builtin_amdgcn_mfma_f32_16x16x32_bf16(av, w0[kk], a0, 0, 0, 0);
            a1 = __builtin_amdgcn_mfma_f32_16x16x32_bf16(av, w1[kk], a1, 0, 0, 0);
        }
        // C row r = edge 4*hi+r of THIS tile; store at its own position.
        int tb = pstart + it * 16;
        #pragma unroll
        for (int r = 0; r < 4; ++r) {
            int row = tb + 4 * hi + r;
            if (row < pend)
                msg[(size_t)row * 16 + row16] = pk2(a0[r], a1[r]);
        }
        r2 = r2N; fa = faN; fb = fbN;
    }
}

// -------- Phase B: per-bin reduce over 9 contiguous runs --------------------
__global__ __launch_bounds__(256, 8) void bconv_reduceS(
    const unsigned* __restrict__ msg, const unsigned char* __restrict__ dloc8,
    const int* __restrict__ keybase, int nbin, float* __restrict__ out, int N)
{
    __shared__ unsigned short perm[CAPB];
    __shared__ int cnt[32], cbase[33], cur[32];

    int t = threadIdx.x, bin = blockIdx.x;
    int g = t >> 3, j = t & 7;
    const uint2* m2 = reinterpret_cast<const uint2*>(msg);

    float aAlo = 0.f, aAhi = 0.f, aBlo = 0.f, aBhi = 0.f;

    for (int c = 0; c < 9; ++c) {
        int k = c * nbin + bin;
        int s0 = keybase[k], s1 = keybase[k + 1];
        for (int chunk = s0; chunk < s1; chunk += CAPB) {
            int clen = min(CAPB, s1 - chunk);
            if (t < 32) cnt[t] = 0;
            __syncthreads();
            for (int i = t; i < clen; i += 256)
                atomicAdd(&cnt[dloc8[chunk + i]], 1);
            __syncthreads();
            if (t == 0) {
                int run = 0;
                #pragma unroll
                for (int c2 = 0; c2 < 32; ++c2) { cbase[c2] = run; run += cnt[c2]; }
                cbase[32] = run;
            }
            __syncthreads();
            if (t < 32) cur[t] = cbase[t];
            __syncthreads();
            for (int i = t; i < clen; i += 256) {
                int d = dloc8[chunk + i];
                int r = atomicAdd(&cur[d], 1);
                perm[r] = (unsigned short)i;
            }
            __syncthreads();

            int lo = cbase[g], hi2 = cbase[g + 1];
            int kk = lo;
            for (; kk + 3 < hi2; kk += 4) {        // 4 loads in flight
                int i0 = perm[kk], i1 = perm[kk + 1], i2 = perm[kk + 2], i3 = perm[kk + 3];
                uint2 v0 = m2[(size_t)(chunk + i0) * 8 + j];
                uint2 v1 = m2[(size_t)(chunk + i1) * 8 + j];
                uint2 v2 = m2[(size_t)(chunk + i2) * 8 + j];
                uint2 v3 = m2[(size_t)(chunk + i3) * 8 + j];
                aAlo += __uint_as_float(v0.x << 16); aAhi += __uint_as_float(v0.x & 0xFFFF0000u);
                aBlo += __uint_as_float(v0.y << 16); aBhi += __uint_as_float(v0.y & 0xFFFF0000u);
                aAlo += __uint_as_float(v1.x << 16); aAhi += __uint_as_float(v1.x & 0xFFFF0000u);
                aBlo += __uint_as_float(v1.y << 16); aBhi += __uint_as_float(v1.y & 0xFFFF0000u);
                aAlo += __uint_as_float(v2.x << 16); aAhi += __uint_as_float(v2.x & 0xFFFF0000u);
                aBlo += __uint_as_float(v2.y << 16); aBhi += __uint_as_float(v2.y & 0xFFFF0000u);
                aAlo += __uint_as_float(v3.x << 16); aAhi += __uint_as_float(v3.x & 0xFFFF0000u);
                aBlo += __uint_as_float(v3.y << 16); aBhi += __uint_as_float(v3.y & 0xFFFF0000u);
            }
            for (; kk < hi2; ++kk) {
                int i0 = perm[kk];
                uint2 v0 = m2[(size_t)(chunk + i0) * 8 + j];
                aAlo += __uint_as_float(v0.x << 16); aAhi += __uint_as_float(v0.x & 0xFFFF0000u);
                aBlo += __uint_as_float(v0.y << 16); aBhi += __uint_as_float(v0.y & 0xFFFF0000u);
            }
            __syncthreads();
        }
    }

    int node = bin * BINSZ + g;
    if (node < N) {
        float2 lo2; lo2.x = aAlo; lo2.y = aBlo;
        float2 hi2v; hi2v.x = aAhi; hi2v.y = aBhi;
        *reinterpret_cast<float2*>(&out[(size_t)node * F + 2 * j])      = lo2;
        *reinterpret_cast<float2*>(&out[(size_t)node * F + 16 + 2 * j]) = hi2v;
    }
}

// ====================== FALLBACK 1 (R3 path): cell sort + global atomics ====
__global__ __launch_bounds__(256) void hist_kernel(
    const float* __restrict__ attr, int E, int* __restrict__ counts)
{
    __shared__ int hh[9];
    int b = blockIdx.x, t = threadIdx.x;
    if (t < 9) hh[t] = 0;
    __syncthreads();
    int start = b * OSCH, end = min(start + OSCH, E);
    for (int e = start + t; e < end; e += 256) {
        float2 a = reinterpret_cast<const float2*>(attr)[e];
        float tx = fminf(fmaxf((a.x + 1.0f) * 1.5f, 0.f), 3.f);
        float ty = fminf(fmaxf((a.y + 1.0f) * 1.5f, 0.f), 3.f);
        atomicAdd(&hh[min((int)tx, 2) * 3 + min((int)ty, 2)], 1);
    }
    __syncthreads();
    if (t < 9) counts[b * 9 + t] = hh[t];
}

__global__ __launch_bounds__(512) void scan_kernel(
    int* __restrict__ ws, int* __restrict__ counts, int nblk)
{
    __shared__ int s[OMAXNBLK * 9];
    __shared__ int tot[9];
    __shared__ int coff[9];
    int n = nblk * 9;
    for (int i = threadIdx.x; i < n; i += 512) s[i] = counts[i];
    __syncthreads();
    if (threadIdx.x < 9) {
        int c = threadIdx.x, run = 0;
        for (int b = 0; b < nblk; ++b) {
            int v = s[b * 9 + c];
            s[b * 9 + c] = run;
            run += v;
        }
        tot[c] = run;
    }
    __syncthreads();
    if (threadIdx.x == 0) {
        int off = 0, boff = 0;
        for (int c = 0; c < 9; ++c) {
            ws[c] = off;  coff[c] = off;
            ws[16 + c] = boff;
            off  += tot[c];
            boff += (tot[c] + EPB - 1) / EPB;
        }
        ws[9] = off;
        ws[16 + 9] = boff;
    }
    __syncthreads();
    for (int i = threadIdx.x; i < n; i += 512)
        counts[i] = s[i] + coff[i % 9];
}

__global__ __launch_bounds__(256) void scatter_kernel(
    const float* __restrict__ attr, int E,
    const int* __restrict__ bases, int* __restrict__ sorted)
{
    __shared__ int cur9[9];
    int b = blockIdx.x, t = threadIdx.x;
    if (t < 9) cur9[t] = bases[b * 9 + t];
    __syncthreads();
    int start = b * OSCH, end = min(start + OSCH, E);
    for (int e = start + t; e < end; e += 256) {
        float2 a = reinterpret_cast<const float2*>(attr)[e];
        float tx = fminf(fmaxf((a.x + 1.0f) * 1.5f, 0.f), 3.f);
        float ty = fminf(fmaxf((a.y + 1.0f) * 1.5f, 0.f), 3.f);
        int c = min((int)tx, 2) * 3 + min((int)ty, 2);
        int pos = atomicAdd(&cur9[c], 1);
        sorted[pos] = e;
    }
}

__global__ __launch_bounds__(256) void bconv_mfma(
    const float* __restrict__ x_j, const int* __restrict__ ei,
    const float* __restrict__ attr, const float* __restrict__ weight,
    const int* __restrict__ ws, const int* __restrict__ sorted,
    float* __restrict__ out, int E)
{
    int b = blockIdx.x;
    const int* blkoff = ws + 16;
    if (b >= blkoff[9]) return;
    int c = 0;
    #pragma unroll
    for (int q = 1; q < 9; ++q) c += (b >= blkoff[q]) ? 1 : 0;
    int kx0 = c / 3, ky0 = c - 3 * (c / 3);
    int local  = b - blkoff[c];
    int cstart = ws[c], cend = ws[c + 1];
    int pstart = cstart + local * EPB;
    int pend   = min(pstart + EPB, cend);

    int t = threadIdx.x;
    int wid = t >> 6, lane = t & 63;
    int row16 = lane & 15, hi = lane >> 4;

    short8 wb[4][2];
    #pragma unroll
    for (int kk = 0; kk < 4; ++kk) {
        int ks = (kx0 + (kk >> 1)) * NB + (ky0 + (kk & 1));
        const float* wp = weight + (size_t)ks * F * F;
        #pragma unroll
        for (int n = 0; n < 2; ++n) {
            short8 v;
            #pragma unroll
            for (int j = 0; j < 8; ++j)
                v[j] = f2bf(wp[(8 * hi + j) * F + row16 + 16 * n]);
            wb[kk][n] = v;
        }
    }

    int wstart = pstart + wid * (EPB / 4);
    int wend   = min(wstart + (EPB / 4), pend);
    if (wstart >= wend) return;

    int ntiles = (wend - wstart + 15) >> 4;
    for (int tt = 0; tt < ntiles; ++tt) {
        int p = wstart + tt * 16 + row16;
        bool v = p < wend;
        int pp = v ? p : wstart;
        int e  = sorted[pp];
        int dst = ei[e];
        int srcn = ei[E + e];
        float2 a = reinterpret_cast<const float2*>(attr)[e];
        const float4* xr = reinterpret_cast<const float4*>(x_j + (size_t)srcn * F);
        float4 fa = xr[2 * hi];
        float4 fb = xr[2 * hi + 1];

        float fx = (a.x + 1.0f) * 1.5f - (float)kx0;
        float fy = (a.y + 1.0f) * 1.5f - (float)ky0;
        float vs = v ? 1.f : 0.f;
        float bx0 = (1.f - fx) * vs, bx1 = fx * vs;
        float bc[4] = { bx0 * (1.f - fy), bx0 * fy, bx1 * (1.f - fy), bx1 * fy };

        f32x4 a0 = {0,0,0,0}, a1 = {0,0,0,0};
        #pragma unroll
        for (int kk = 0; kk < 4; ++kk) {
            float s = bc[kk];
            uint4v u;
            u[0] = pk2(fa.x * s, fa.y * s);
            u[1] = pk2(fa.z * s, fa.w * s);
            u[2] = pk2(fb.x * s, fb.y * s);
            u[3] = pk2(fb.z * s, fb.w * s);
            short8 av = __builtin_bit_cast(short8, u);
            a0 = __builtin_amdgcn_mfma_f32_16x16x32_bf16(av, wb[kk][0], a0, 0, 0, 0);
            a1 = __builtin_amdgcn_mfma_f32_16x16x32_bf16(av, wb[kk][1], a1, 0, 0, 0);
        }
        #pragma unroll
        for (int r = 0; r < 4; ++r) {
            int d = __shfl(v ? dst : -1, 4 * hi + r, 64);
            if (d >= 0) {
                atomicAdd(&out[(size_t)d * F + row16],      a0[r]);
                atomicAdd(&out[(size_t)d * F + 16 + row16], a1[r]);
            }
        }
    }
}

// ====================== FALLBACK 2: f32 VALU path ===========================
__global__ __launch_bounds__(256) void bconv_fallback(
    const float* __restrict__ x_j, const int* __restrict__ ei,
    const float* __restrict__ attr, const float* __restrict__ weight,
    float* __restrict__ out, int E)
{
    __shared__ float wl[16 * F * F];
    __shared__ float featl[8][F];
    for (int idx = threadIdx.x; idx < 4096; idx += 256)
        reinterpret_cast<float4*>(wl)[idx] = reinterpret_cast<const float4*>(weight)[idx];
    __syncthreads();

    int lane = threadIdx.x & 31, eslot = threadIdx.x >> 5;
    for (int p = blockIdx.x * 8 + eslot; p < E; p += gridDim.x * 8) {
        int dst = ei[p], srcn = ei[E + p];
        float ax = attr[2 * p], ay = attr[2 * p + 1];
        featl[eslot][lane] = x_j[(size_t)srcn * F + lane];
        float tx = (ax + 1.0f) * 1.5f, ty = (ay + 1.0f) * 1.5f;
        int kx0 = min(max((int)tx, 0), 2), ky0 = min(max((int)ty, 0), 2);
        float fx = tx - kx0, fy = ty - ky0;
        float bcv[4] = { (1.0f - fx) * (1.0f - fy), (1.0f - fx) * fy,
                         fx * (1.0f - fy), fx * fy };
        float msg = 0.f;
        const float4* f4 = reinterpret_cast<const float4*>(&featl[eslot][0]);
        #pragma unroll
        for (int kk = 0; kk < 4; ++kk) {
            int k = (kx0 + (kk >> 1)) * NB + (ky0 + (kk & 1));
            const float* wk = wl + k * F * F;
            float a2 = 0.f;
            #pragma unroll
            for (int j = 0; j < 8; ++j) {
                float4 f = f4[j];
                a2 = fmaf(f.x, wk[(4 * j + 0) * F + lane], a2);
                a2 = fmaf(f.y, wk[(4 * j + 1) * F + lane], a2);
                a2 = fmaf(f.z, wk[(4 * j + 2) * F + lane], a2);
                a2 = fmaf(f.w, wk[(4 * j + 3) * F + lane], a2);
            }
            msg = fmaf(bcv[kk], a2, msg);
        }
        atomicAdd(&out[(size_t)dst * F + lane], msg);
    }
}

extern "C" void kernel_launch(void* const* d_in, const int* in_sizes, int n_in,
                              void* d_out, int out_size, void* d_ws, size_t ws_size,
                              hipStream_t stream) {
    const float* x_j    = (const float*)d_in[1];
    const int*   ei     = (const int*)d_in[2];
    const float* attr   = (const float*)d_in[3];
    const float* weight = (const float*)d_in[4];
    float* out = (float*)d_out;
    int E = in_sizes[2] / 2;
    int N = in_sizes[0] / F;

    int nbin = (N + BINSZ - 1) >> BINSH;
    int nkey = 9 * nbin;
    int nblk2 = (E + SCH2 - 1) / SCH2;

    // --- new-path ws layout (ints) ---
    size_t o_counts  = 0;                                   // nblk2*nkey
    size_t o_keytot  = o_counts + (size_t)nblk2 * nkey;     // nkey
    size_t o_keybase = o_keytot + nkey;                     // nkey+1
    size_t o_blkoff  = o_keybase + nkey + 1;                // 10
    size_t o_wbf     = (o_blkoff + 10 + 3) & ~(size_t)3;    // 8192 ints
    size_t o_dloc    = o_wbf + 8192;                        // ceil(E/4)
    size_t o_rec     = (o_dloc + (E + 3) / 4 + 1) & ~(size_t)1;  // 2E (uint2)
    size_t o_msg     = (o_rec + 2 * (size_t)E + 3) & ~(size_t)3; // 16E
    size_t need_new  = (o_msg + 16 * (size_t)E) * sizeof(int);

    // --- old-path ws layout ---
    int nblk_sort = (E + OSCH - 1) / OSCH;
    int sorted_off = 32 + ((nblk_sort * 9 + 15) & ~15);
    size_t need_old = (size_t)(sorted_off + E) * sizeof(int);

    if (nbin <= MAXBIN2 && N <= MAXBIN2 * BINSZ && nblk2 <= NBLK2MAX &&
        ws_size >= need_new) {
        int* ws = (int*)d_ws;
        int* counts   = ws + o_counts;
        int* keytot   = ws + o_keytot;
        int* keybase  = ws + o_keybase;
        int* blkoff   = ws + o_blkoff;
        short* wbf    = (short*)(ws + o_wbf);
        unsigned char* dloc8 = (unsigned char*)(ws + o_dloc);
        uint2* rec    = (uint2*)(ws + o_rec);
        unsigned* msg = (unsigned*)(ws + o_msg);

        int nkb = (nkey + 255) / 256;
        w_prep<<<64, 256, 0, stream>>>(weight, wbf);
        k1_hist<<<nblk2, 256, 0, stream>>>(ei, attr, E, nbin, nkey, counts);
        k2a_tot<<<nkb, 256, 0, stream>>>(counts, keytot, nkey, nblk2);
        k2b_scan<<<1, 256, 0, stream>>>(keytot, keybase, blkoff, nkey, nbin, E);
        k2c_base<<<nkb, 256, 0, stream>>>(counts, keybase, nkey, nblk2);
        k3_scat<<<nblk2, 256, 0, stream>>>(ei, attr, E, nbin, nkey, counts, rec, dloc8);
        int nblkA = (E + EPB - 1) / EPB + 9;
        bconv_msgS<<<nblkA, 256, 0, stream>>>(x_j, wbf, keybase, blkoff, rec, msg, nbin);
        bconv_reduceS<<<nbin, 256, 0, stream>>>(msg, dloc8, keybase, nbin, out, N);
    } else if (nblk_sort <= OMAXNBLK && ws_size >= need_old) {
        hipMemsetAsync(d_out, 0, (size_t)out_size * sizeof(float), stream);
        int* ws      = (int*)d_ws;
        int* counts  = ws + 32;
        int* sorted  = ws + sorted_off;
        hist_kernel<<<nblk_sort, 256, 0, stream>>>(attr, E, counts);
        scan_kernel<<<1, 512, 0, stream>>>(ws, counts, nblk_sort);
        scatter_kernel<<<nblk_sort, 256, 0, stream>>>(attr, E, counts, sorted);
        int nblk_main = (E + EPB - 1) / EPB + 9;
        bconv_mfma<<<nblk_main, 256, 0, stream>>>(x_j, ei, attr, weight, ws, sorted, out, E);
    } else {
        hipMemsetAsync(d_out, 0, (size_t)out_size * sizeof(float), stream);
        bconv_fallback<<<2048, 256, 0, stream>>>(x_j, ei, attr, weight, out, E);
    }
}

// Round 12
// 98.771 us; speedup vs baseline: 1.7268x; 1.7268x over previous
//
#include <hip/hip_runtime.h>
#include <hip/hip_bf16.h>

typedef short short8 __attribute__((ext_vector_type(8)));
typedef float f32x4 __attribute__((ext_vector_type(4)));
typedef unsigned uint4v __attribute__((ext_vector_type(4)));

#define F 32
#define NB 4
#define BINSH 5        // 32 nodes per dst-bin
#define BINSZ 32
#define EPB 512        // edges per Phase-A block
#define SCH 4096       // edges per scatter block
#define MAXBIN 2048
#define CAPB 2048      // reduce: rows permuted per chunk
// old path constants
#define OSCH 2048
#define OMAXNBLK 1024

__device__ __forceinline__ short f2bf(float f) {   // RNE f32->bf16
    unsigned u = __float_as_uint(f);
    unsigned r = (u + 0x7FFFu + ((u >> 16) & 1u)) >> 16;
    return (short)r;
}

__device__ __forceinline__ unsigned pk2(float a, float b) {  // packed bf16 pair
    __hip_bfloat162 h = __float22bfloat162_rn(make_float2(a, b));
    union { __hip_bfloat162 h; unsigned u; } cv; cv.h = h; return cv.u;
}

// -------- tiny zero kernel (replaces 40-µs in-graph hipMemsetAsync) ---------
__global__ __launch_bounds__(256) void zero_kernel(int* __restrict__ p, int n) {
    for (int i = threadIdx.x; i < n; i += 256) p[i] = 0;
}

// -------- weight prep: bf16 B-fragment layout into ws (32 KB, L2-resident) --
__global__ __launch_bounds__(256) void w_prep(
    const float* __restrict__ w, short* __restrict__ wbf)
{
    int idx = blockIdx.x * 256 + threadIdx.x;   // 64 x 256 = 16384
    int k = idx >> 10, rem = idx & 1023, i = rem >> 5, o = rem & 31;
    int slot = (((k * 4 + (i >> 3)) * 2 + (o >> 4)) * 16 + (o & 15)) * 8 + (i & 7);
    wbf[slot] = f2bf(w[idx]);
}

// -------- combined hist: dst-bin (LDS) + cell (LDS), flush to global --------
__global__ __launch_bounds__(256) void h2_kernel(
    const int* __restrict__ ei, const float* __restrict__ attr, int E, int nbin,
    int* __restrict__ bincnt, int* __restrict__ cellcnt)
{
    __shared__ int hb[MAXBIN];
    __shared__ int hc[9];
    int t = threadIdx.x;
    for (int i = t; i < nbin; i += 256) hb[i] = 0;
    if (t < 9) hc[t] = 0;
    __syncthreads();
    int stride = gridDim.x * blockDim.x;
    for (int e = blockIdx.x * blockDim.x + t; e < E; e += stride) {
        int dst = ei[e];
        float2 a = reinterpret_cast<const float2*>(attr)[e];
        float tx = fminf(fmaxf((a.x + 1.0f) * 1.5f, 0.f), 3.f);
        float ty = fminf(fmaxf((a.y + 1.0f) * 1.5f, 0.f), 3.f);
        int kx = min((int)tx, 2), ky = min((int)ty, 2);
        atomicAdd(&hb[dst >> BINSH], 1);
        atomicAdd(&hc[kx * 3 + ky], 1);
    }
    __syncthreads();
    for (int i = t; i < nbin; i += 256)
        if (hb[i]) atomicAdd(&bincnt[i], hb[i]);
    if (t < 9 && hc[t]) atomicAdd(&cellcnt[t], hc[t]);
}

// -------- scan: bins -> binbase/bincur ; cells -> cellbase/cellcur/blkoff ---
__global__ __launch_bounds__(256) void scan2_kernel(
    const int* __restrict__ bincnt, int* __restrict__ binbase,
    int* __restrict__ bincur, const int* __restrict__ cellcnt,
    int* __restrict__ cellbase, int* __restrict__ cellcur,
    int* __restrict__ blkoff, int nbin)
{
    __shared__ int part[256];
    int t = threadIdx.x;
    int chunk = (nbin + 255) / 256;
    int lo = t * chunk, hi = min(lo + chunk, nbin);
    int s = 0;
    for (int q = lo; q < hi; ++q) s += bincnt[q];
    part[t] = s;
    __syncthreads();
    if (t == 0) {
        int run = 0;
        for (int j = 0; j < 256; ++j) { int v = part[j]; part[j] = run; run += v; }
        binbase[nbin] = run;
    }
    __syncthreads();
    int run = part[t];
    for (int q = lo; q < hi; ++q) {
        binbase[q] = run; bincur[q] = run;
        run += bincnt[q];
    }
    if (t == 0) {
        int off = 0, boff = 0;
        for (int c = 0; c < 9; ++c) {
            cellbase[c] = off; cellcur[c] = off; blkoff[c] = boff;
            off  += cellcnt[c];
            boff += (cellcnt[c] + EPB - 1) / EPB;
        }
        cellbase[9] = off; blkoff[9] = boff;
    }
}

// -------- scatter: both orderings in one pass -------------------------------
// cellrec[poscell] = {src, posdst, tx_f32, ty_f32}; dloc8[posdst] = dst&31
__global__ __launch_bounds__(256) void scat2_kernel(
    const int* __restrict__ ei, const float* __restrict__ attr, int E, int nbin,
    int* __restrict__ bincur, int* __restrict__ cellcur,
    uint4* __restrict__ cellrec, unsigned char* __restrict__ dloc8)
{
    __shared__ int hb[MAXBIN];
    __shared__ int hc[9];
    int t = threadIdx.x, b = blockIdx.x;
    int start = b * SCH, end = min(start + SCH, E);
    for (int i = t; i < nbin; i += 256) hb[i] = 0;
    if (t < 9) hc[t] = 0;
    __syncthreads();
    for (int e = start + t; e < end; e += 256) {
        int dst = ei[e];
        float2 a = reinterpret_cast<const float2*>(attr)[e];
        float tx = fminf(fmaxf((a.x + 1.0f) * 1.5f, 0.f), 3.f);
        float ty = fminf(fmaxf((a.y + 1.0f) * 1.5f, 0.f), 3.f);
        int kx = min((int)tx, 2), ky = min((int)ty, 2);
        atomicAdd(&hb[dst >> BINSH], 1);
        atomicAdd(&hc[kx * 3 + ky], 1);
    }
    __syncthreads();
    for (int k = t; k < nbin; k += 256) {
        int c = hb[k];
        if (c) hb[k] = atomicAdd(&bincur[k], c);
    }
    if (t < 9) hc[t] = atomicAdd(&cellcur[t], hc[t]);
    __syncthreads();
    for (int e = start + t; e < end; e += 256) {
        int dst = ei[e];
        int src = ei[E + e];
        float2 a = reinterpret_cast<const float2*>(attr)[e];
        float tx = fminf(fmaxf((a.x + 1.0f) * 1.5f, 0.f), 3.f);
        float ty = fminf(fmaxf((a.y + 1.0f) * 1.5f, 0.f), 3.f);
        int kx = min((int)tx, 2), ky = min((int)ty, 2);
        int pd = atomicAdd(&hb[dst >> BINSH], 1);
        int pc = atomicAdd(&hc[kx * 3 + ky], 1);
        uint4 rec;
        rec.x = (unsigned)src;
        rec.y = (unsigned)pd;
        rec.z = __float_as_uint(tx);
        rec.w = __float_as_uint(ty);
        cellrec[pc] = rec;
        dloc8[pd] = (unsigned char)(dst & (BINSZ - 1));
    }
}

// -------- Phase A: cell-sorted tiles -> per-edge bf16 messages --------------
// msg row (64 B) = 16 u32 words; word w = pack(bf16 col w, bf16 col w+16).
__global__ __launch_bounds__(256, 4) void bconv_msg(
    const float* __restrict__ x_j, const short* __restrict__ wbf,
    const int* __restrict__ cellbase, const int* __restrict__ blkoff,
    const uint4* __restrict__ cellrec, unsigned* __restrict__ msg)
{
    int b = blockIdx.x;
    if (b >= blkoff[9]) return;
    int c = 0;
    #pragma unroll
    for (int q = 1; q < 9; ++q) c += (b >= blkoff[q]) ? 1 : 0;
    int kx0 = c / 3, ky0 = c - 3 * (c / 3);
    int local  = b - blkoff[c];
    int cstart = cellbase[c], cend = cellbase[c + 1];
    int pstart = cstart + local * EPB;
    int pend   = min(pstart + EPB, cend);
    if (pstart >= pend) return;

    int t = threadIdx.x;
    int wid = t >> 6, lane = t & 63;
    int row16 = lane & 15, hi = lane >> 4;

    // B fragments for this cell (8 x 16B loads from L2-resident wbf)
    short8 w0[4], w1[4];
    #pragma unroll
    for (int kk = 0; kk < 4; ++kk) {
        int ks = (kx0 + (kk >> 1)) * NB + (ky0 + (kk & 1));
        w0[kk] = *reinterpret_cast<const short8*>(
            wbf + (((ks * 4 + hi) * 2 + 0) * 16 + row16) * 8);
        w1[kk] = *reinterpret_cast<const short8*>(
            wbf + (((ks * 4 + hi) * 2 + 1) * 16 + row16) * 8);
    }

    const float4* x4 = reinterpret_cast<const float4*>(x_j);
    int ntile = (pend - pstart + 15) >> 4;

    auto fetch = [&](int ti, uint4& rec, float4& fa, float4& fb, int& pdv) {
        int p = pstart + ti * 16 + row16;
        bool v = p < pend;
        int pp = v ? p : pstart;
        rec = cellrec[pp];
        int src = rec.x;
        fa = x4[src * 8 + 2 * hi];
        fb = x4[src * 8 + 2 * hi + 1];
        pdv = v ? (int)rec.y : -1;
    };

    int it = wid;
    uint4 rec; float4 fa, fb; int pdv;
    if (it < ntile) fetch(it, rec, fa, fb, pdv);

    for (; it < ntile; it += 4) {
        uint4 recN; float4 faN, fbN; int pdvN = -1;
        bool hn = (it + 4) < ntile;
        if (hn) fetch(it + 4, recN, faN, fbN, pdvN);   // loads fly under compute

        float tx = __uint_as_float(rec.z), ty = __uint_as_float(rec.w);
        float fx = tx - (float)kx0, fy = ty - (float)ky0;
        float bx0 = 1.f - fx, by0 = 1.f - fy;
        float bc[4] = { bx0 * by0, bx0 * fy, fx * by0, fx * fy };
        float fl[8] = { fa.x, fa.y, fa.z, fa.w, fb.x, fb.y, fb.z, fb.w };

        f32x4 a0 = {0,0,0,0}, a1 = {0,0,0,0};
        #pragma unroll
        for (int kk = 0; kk < 4; ++kk) {
            float s = bc[kk];
            uint4v u;
            u[0] = pk2(fl[0] * s, fl[1] * s);
            u[1] = pk2(fl[2] * s, fl[3] * s);
            u[2] = pk2(fl[4] * s, fl[5] * s);
            u[3] = pk2(fl[6] * s, fl[7] * s);
            short8 av = __builtin_bit_cast(short8, u);
            a0 = __builtin_amdgcn_mfma_f32_16x16x32_bf16(av, w0[kk], a0, 0, 0, 0);
            a1 = __builtin_amdgcn_mfma_f32_16x16x32_bf16(av, w1[kk], a1, 0, 0, 0);
        }
        // C row r = edge 4*hi+r ; word row16 = (col row16, col row16+16).
        #pragma unroll
        for (int r = 0; r < 4; ++r) {
            int pd = __shfl(pdv, 4 * hi + r, 64);
            if (pd >= 0)
                msg[(size_t)pd * 16 + row16] = pk2(a0[r], a1[r]);
        }
        rec = recN; fa = faN; fb = fbN; pdv = pdvN;
    }
}

// -------- Phase B: per-node register accumulation over bf16 rows ------------
__global__ __launch_bounds__(256, 8) void bconv_reduce(
    const unsigned* __restrict__ msg, const unsigned char* __restrict__ dloc8,
    const int* __restrict__ binbase, float* __restrict__ out, int N)
{
    __shared__ unsigned short perm[CAPB];
    __shared__ int cnt[32], cbase[33], cur[32];

    int t = threadIdx.x, bin = blockIdx.x;
    int g = t >> 3, j = t & 7;
    int s0 = binbase[bin], s1 = binbase[bin + 1];
    const uint2* m2 = reinterpret_cast<const uint2*>(msg);

    float aAlo = 0.f, aAhi = 0.f, aBlo = 0.f, aBhi = 0.f;

    for (int chunk = s0; chunk < s1; chunk += CAPB) {
        int clen = min(CAPB, s1 - chunk);
        if (t < 32) cnt[t] = 0;
        __syncthreads();
        for (int i = t; i < clen; i += 256)
            atomicAdd(&cnt[dloc8[chunk + i]], 1);
        __syncthreads();
        if (t == 0) {
            int run = 0;
            #pragma unroll
            for (int c2 = 0; c2 < 32; ++c2) { cbase[c2] = run; run += cnt[c2]; }
            cbase[32] = run;
        }
        __syncthreads();
        if (t < 32) cur[t] = cbase[t];
        __syncthreads();
        for (int i = t; i < clen; i += 256) {
            int d = dloc8[chunk + i];
            int r = atomicAdd(&cur[d], 1);
            perm[r] = (unsigned short)i;
        }
        __syncthreads();

        int lo = cbase[g], hi2 = cbase[g + 1];
        int k = lo;
        for (; k + 3 < hi2; k += 4) {           // 4 independent loads in flight
            int i0 = perm[k], i1 = perm[k + 1], i2 = perm[k + 2], i3 = perm[k + 3];
            uint2 v0 = m2[(size_t)(chunk + i0) * 8 + j];
            uint2 v1 = m2[(size_t)(chunk + i1) * 8 + j];
            uint2 v2 = m2[(size_t)(chunk + i2) * 8 + j];
            uint2 v3 = m2[(size_t)(chunk + i3) * 8 + j];
            aAlo += __uint_as_float(v0.x << 16); aAhi += __uint_as_float(v0.x & 0xFFFF0000u);
            aBlo += __uint_as_float(v0.y << 16); aBhi += __uint_as_float(v0.y & 0xFFFF0000u);
            aAlo += __uint_as_float(v1.x << 16); aAhi += __uint_as_float(v1.x & 0xFFFF0000u);
            aBlo += __uint_as_float(v1.y << 16); aBhi += __uint_as_float(v1.y & 0xFFFF0000u);
            aAlo += __uint_as_float(v2.x << 16); aAhi += __uint_as_float(v2.x & 0xFFFF0000u);
            aBlo += __uint_as_float(v2.y << 16); aBhi += __uint_as_float(v2.y & 0xFFFF0000u);
            aAlo += __uint_as_float(v3.x << 16); aAhi += __uint_as_float(v3.x & 0xFFFF0000u);
            aBlo += __uint_as_float(v3.y << 16); aBhi += __uint_as_float(v3.y & 0xFFFF0000u);
        }
        for (; k < hi2; ++k) {
            int i0 = perm[k];
            uint2 v0 = m2[(size_t)(chunk + i0) * 8 + j];
            aAlo += __uint_as_float(v0.x << 16); aAhi += __uint_as_float(v0.x & 0xFFFF0000u);
            aBlo += __uint_as_float(v0.y << 16); aBhi += __uint_as_float(v0.y & 0xFFFF0000u);
        }
        __syncthreads();                        // perm reused next chunk
    }

    int node = bin * BINSZ + g;
    if (node < N) {
        float2 lo2; lo2.x = aAlo; lo2.y = aBlo;
        float2 hi2v; hi2v.x = aAhi; hi2v.y = aBhi;
        *reinterpret_cast<float2*>(&out[(size_t)node * F + 2 * j])      = lo2;
        *reinterpret_cast<float2*>(&out[(size_t)node * F + 16 + 2 * j]) = hi2v;
    }
}

// ====================== FALLBACK 1 (R3 path): cell sort + global atomics ====
__global__ __launch_bounds__(256) void hist_kernel(
    const float* __restrict__ attr, int E, int* __restrict__ counts)
{
    __shared__ int hh[9];
    int b = blockIdx.x, t = threadIdx.x;
    if (t < 9) hh[t] = 0;
    __syncthreads();
    int start = b * OSCH, end = min(start + OSCH, E);
    for (int e = start + t; e < end; e += 256) {
        float2 a = reinterpret_cast<const float2*>(attr)[e];
        float tx = fminf(fmaxf((a.x + 1.0f) * 1.5f, 0.f), 3.f);
        float ty = fminf(fmaxf((a.y + 1.0f) * 1.5f, 0.f), 3.f);
        atomicAdd(&hh[min((int)tx, 2) * 3 + min((int)ty, 2)], 1);
    }
    __syncthreads();
    if (t < 9) counts[b * 9 + t] = hh[t];
}

__global__ __launch_bounds__(512) void scan_kernel(
    int* __restrict__ ws, int* __restrict__ counts, int nblk)
{
    __shared__ int s[OMAXNBLK * 9];
    __shared__ int tot[9];
    __shared__ int coff[9];
    int n = nblk * 9;
    for (int i = threadIdx.x; i < n; i += 512) s[i] = counts[i];
    __syncthreads();
    if (threadIdx.x < 9) {
        int c = threadIdx.x, run = 0;
        for (int b = 0; b < nblk; ++b) {
            int v = s[b * 9 + c];
            s[b * 9 + c] = run;
            run += v;
        }
        tot[c] = run;
    }
    __syncthreads();
    if (threadIdx.x == 0) {
        int off = 0, boff = 0;
        for (int c = 0; c < 9; ++c) {
            ws[c] = off;  coff[c] = off;
            ws[16 + c] = boff;
            off  += tot[c];
            boff += (tot[c] + EPB - 1) / EPB;
        }
        ws[9] = off;
        ws[16 + 9] = boff;
    }
    __syncthreads();
    for (int i = threadIdx.x; i < n; i += 512)
        counts[i] = s[i] + coff[i % 9];
}

__global__ __launch_bounds__(256) void scatter_kernel(
    const float* __restrict__ attr, int E,
    const int* __restrict__ bases, int* __restrict__ sorted)
{
    __shared__ int cur9[9];
    int b = blockIdx.x, t = threadIdx.x;
    if (t < 9) cur9[t] = bases[b * 9 + t];
    __syncthreads();
    int start = b * OSCH, end = min(start + OSCH, E);
    for (int e = start + t; e < end; e += 256) {
        float2 a = reinterpret_cast<const float2*>(attr)[e];
        float tx = fminf(fmaxf((a.x + 1.0f) * 1.5f, 0.f), 3.f);
        float ty = fminf(fmaxf((a.y + 1.0f) * 1.5f, 0.f), 3.f);
        int c = min((int)tx, 2) * 3 + min((int)ty, 2);
        int pos = atomicAdd(&cur9[c], 1);
        sorted[pos] = e;
    }
}

__global__ __launch_bounds__(256) void bconv_mfma(
    const float* __restrict__ x_j, const int* __restrict__ ei,
    const float* __restrict__ attr, const float* __restrict__ weight,
    const int* __restrict__ ws, const int* __restrict__ sorted,
    float* __restrict__ out, int E)
{
    int b = blockIdx.x;
    const int* blkoff = ws + 16;
    if (b >= blkoff[9]) return;
    int c = 0;
    #pragma unroll
    for (int q = 1; q < 9; ++q) c += (b >= blkoff[q]) ? 1 : 0;
    int kx0 = c / 3, ky0 = c - 3 * (c / 3);
    int local  = b - blkoff[c];
    int cstart = ws[c], cend = ws[c + 1];
    int pstart = cstart + local * EPB;
    int pend   = min(pstart + EPB, cend);

    int t = threadIdx.x;
    int wid = t >> 6, lane = t & 63;
    int row16 = lane & 15, hi = lane >> 4;

    short8 wb[4][2];
    #pragma unroll
    for (int kk = 0; kk < 4; ++kk) {
        int ks = (kx0 + (kk >> 1)) * NB + (ky0 + (kk & 1));
        const float* wp = weight + (size_t)ks * F * F;
        #pragma unroll
        for (int n = 0; n < 2; ++n) {
            short8 v;
            #pragma unroll
            for (int j = 0; j < 8; ++j)
                v[j] = f2bf(wp[(8 * hi + j) * F + row16 + 16 * n]);
            wb[kk][n] = v;
        }
    }

    int wstart = pstart + wid * (EPB / 4);
    int wend   = min(wstart + (EPB / 4), pend);
    if (wstart >= wend) return;

    int ntiles = (wend - wstart + 15) >> 4;
    for (int tt = 0; tt < ntiles; ++tt) {
        int p = wstart + tt * 16 + row16;
        bool v = p < wend;
        int pp = v ? p : wstart;
        int e  = sorted[pp];
        int dst = ei[e];
        int srcn = ei[E + e];
        float2 a = reinterpret_cast<const float2*>(attr)[e];
        const float4* xr = reinterpret_cast<const float4*>(x_j + (size_t)srcn * F);
        float4 fa = xr[2 * hi];
        float4 fb = xr[2 * hi + 1];

        float fx = (a.x + 1.0f) * 1.5f - (float)kx0;
        float fy = (a.y + 1.0f) * 1.5f - (float)ky0;
        float vs = v ? 1.f : 0.f;
        float bx0 = (1.f - fx) * vs, bx1 = fx * vs;
        float bc[4] = { bx0 * (1.f - fy), bx0 * fy, bx1 * (1.f - fy), bx1 * fy };

        f32x4 a0 = {0,0,0,0}, a1 = {0,0,0,0};
        #pragma unroll
        for (int kk = 0; kk < 4; ++kk) {
            float s = bc[kk];
            uint4v u;
            u[0] = pk2(fa.x * s, fa.y * s);
            u[1] = pk2(fa.z * s, fa.w * s);
            u[2] = pk2(fb.x * s, fb.y * s);
            u[3] = pk2(fb.z * s, fb.w * s);
            short8 av = __builtin_bit_cast(short8, u);
            a0 = __builtin_amdgcn_mfma_f32_16x16x32_bf16(av, wb[kk][0], a0, 0, 0, 0);
            a1 = __builtin_amdgcn_mfma_f32_16x16x32_bf16(av, wb[kk][1], a1, 0, 0, 0);
        }
        #pragma unroll
        for (int r = 0; r < 4; ++r) {
            int d = __shfl(v ? dst : -1, 4 * hi + r, 64);
            if (d >= 0) {
                atomicAdd(&out[(size_t)d * F + row16],      a0[r]);
                atomicAdd(&out[(size_t)d * F + 16 + row16], a1[r]);
            }
        }
    }
}

// ====================== FALLBACK 2: f32 VALU path ===========================
__global__ __launch_bounds__(256) void bconv_fallback(
    const float* __restrict__ x_j, const int* __restrict__ ei,
    const float* __restrict__ attr, const float* __restrict__ weight,
    float* __restrict__ out, int E)
{
    __shared__ float wl[16 * F * F];
    __shared__ float featl[8][F];
    for (int idx = threadIdx.x; idx < 4096; idx += 256)
        reinterpret_cast<float4*>(wl)[idx] = reinterpret_cast<const float4*>(weight)[idx];
    __syncthreads();

    int lane = threadIdx.x & 31, eslot = threadIdx.x >> 5;
    for (int p = blockIdx.x * 8 + eslot; p < E; p += gridDim.x * 8) {
        int dst = ei[p], srcn = ei[E + p];
        float ax = attr[2 * p], ay = attr[2 * p + 1];
        featl[eslot][lane] = x_j[(size_t)srcn * F + lane];
        float tx = (ax + 1.0f) * 1.5f, ty = (ay + 1.0f) * 1.5f;
        int kx0 = min(max((int)tx, 0), 2), ky0 = min(max((int)ty, 0), 2);
        float fx = tx - kx0, fy = ty - ky0;
        float bcv[4] = { (1.0f - fx) * (1.0f - fy), (1.0f - fx) * fy,
                         fx * (1.0f - fy), fx * fy };
        float msg = 0.f;
        const float4* f4 = reinterpret_cast<const float4*>(&featl[eslot][0]);
        #pragma unroll
        for (int kk = 0; kk < 4; ++kk) {
            int k = (kx0 + (kk >> 1)) * NB + (ky0 + (kk & 1));
            const float* wk = wl + k * F * F;
            float a2 = 0.f;
            #pragma unroll
            for (int j = 0; j < 8; ++j) {
                float4 f = f4[j];
                a2 = fmaf(f.x, wk[(4 * j + 0) * F + lane], a2);
                a2 = fmaf(f.y, wk[(4 * j + 1) * F + lane], a2);
                a2 = fmaf(f.z, wk[(4 * j + 2) * F + lane], a2);
                a2 = fmaf(f.w, wk[(4 * j + 3) * F + lane], a2);
            }
            msg = fmaf(bcv[kk], a2, msg);
        }
        atomicAdd(&out[(size_t)dst * F + lane], msg);
    }
}

extern "C" void kernel_launch(void* const* d_in, const int* in_sizes, int n_in,
                              void* d_out, int out_size, void* d_ws, size_t ws_size,
                              hipStream_t stream) {
    const float* x_j    = (const float*)d_in[1];
    const int*   ei     = (const int*)d_in[2];
    const float* attr   = (const float*)d_in[3];
    const float* weight = (const float*)d_in[4];
    float* out = (float*)d_out;
    int E = in_sizes[2] / 2;
    int N = in_sizes[0] / F;

    int nbin = (N + BINSZ - 1) >> BINSH;

    // --- new-path ws layout (ints) ---
    int o_bincnt   = 0;                       // nbin
    int o_cellcnt  = o_bincnt + nbin;         // 9
    int o_binbase  = o_cellcnt + 9;           // nbin+1
    int o_bincur   = o_binbase + nbin + 1;    // nbin
    int o_cellbase = o_bincur + nbin;         // 10
    int o_cellcur  = o_cellbase + 10;         // 9
    int o_blkoff   = o_cellcur + 9;           // 10
    int o_wbf      = (o_blkoff + 10 + 3) & ~3;          // 8192 ints
    int o_dloc     = o_wbf + 8192;                      // ceil(E/4) ints
    int o_cellrec  = (o_dloc + (E + 3) / 4 + 3) & ~3;   // 4E ints (uint4)
    size_t o_msg   = (size_t)((o_cellrec + 4 * (size_t)E + 3) & ~3);
    size_t need_new = (o_msg + 16 * (size_t)E) * sizeof(int);   // bf16 rows: 64 B/edge

    // --- old-path ws layout ---
    int nblk_sort = (E + OSCH - 1) / OSCH;
    int sorted_off = 32 + ((nblk_sort * 9 + 15) & ~15);
    size_t need_old = (size_t)(sorted_off + E) * sizeof(int);

    if (nbin <= MAXBIN && N <= 65536 && E < (1 << 24) && ws_size >= need_new) {
        int* ws = (int*)d_ws;
        short* wbf = (short*)(ws + o_wbf);
        unsigned char* dloc8 = (unsigned char*)(ws + o_dloc);
        uint4* cellrec = (uint4*)(ws + o_cellrec);
        unsigned* msg = (unsigned*)(ws + o_msg);

        zero_kernel<<<1, 256, 0, stream>>>(ws, nbin + 9);   // no hipMemsetAsync
        w_prep<<<64, 256, 0, stream>>>(weight, wbf);
        h2_kernel<<<256, 256, 0, stream>>>(ei, attr, E, nbin,
                                           ws + o_bincnt, ws + o_cellcnt);
        scan2_kernel<<<1, 256, 0, stream>>>(ws + o_bincnt, ws + o_binbase,
                                            ws + o_bincur, ws + o_cellcnt,
                                            ws + o_cellbase, ws + o_cellcur,
                                            ws + o_blkoff, nbin);
        scat2_kernel<<<(E + SCH - 1) / SCH, 256, 0, stream>>>(
            ei, attr, E, nbin, ws + o_bincur, ws + o_cellcur, cellrec, dloc8);
        int nblkA = (E + EPB - 1) / EPB + 9;
        bconv_msg<<<nblkA, 256, 0, stream>>>(x_j, wbf, ws + o_cellbase,
                                             ws + o_blkoff, cellrec, msg);
        bconv_reduce<<<nbin, 256, 0, stream>>>(msg, dloc8, ws + o_binbase, out, N);
    } else if (nblk_sort <= OMAXNBLK && ws_size >= need_old) {
        hipMemsetAsync(d_out, 0, (size_t)out_size * sizeof(float), stream);
        int* ws      = (int*)d_ws;
        int* counts  = ws + 32;
        int* sorted  = ws + sorted_off;
        hist_kernel<<<nblk_sort, 256, 0, stream>>>(attr, E, counts);
        scan_kernel<<<1, 512, 0, stream>>>(ws, counts, nblk_sort);
        scatter_kernel<<<nblk_sort, 256, 0, stream>>>(attr, E, counts, sorted);
        int nblk_main = (E + EPB - 1) / EPB + 9;
        bconv_mfma<<<nblk_main, 256, 0, stream>>>(x_j, ei, attr, weight, ws, sorted, out, E);
    } else {
        hipMemsetAsync(d_out, 0, (size_t)out_size * sizeof(float), stream);
        bconv_fallback<<<2048, 256, 0, stream>>>(x_j, ei, attr, weight, out, E);
    }
}